// Round 3
// baseline (179.456 us; speedup 1.0000x reference)
//
#include <hip/hip_runtime.h>
#include <hip/hip_bf16.h>

// SegmentDeactivation: KAN layer folded into one bf16 GEMM.
// K = 512*36 (dense-ified 4-sparse cubic B-spline bases) + 512 (silu(x)·W_base)
//   + 512 (x·masked-slope) + 1024 zero pad = 20480. bias = sum of masked intercepts.
// R3: BK=64 K-loop (pad K to 20480), XOR-swizzled LDS to kill bank conflicts,
//     SPLITS=32 split-K fp32 partials + reduce, ks-grouped blocks for XCD-L2 locality.

typedef unsigned short u16;
typedef unsigned int u32;
typedef unsigned long long u64;
typedef __attribute__((ext_vector_type(8))) short short8;
typedef __attribute__((ext_vector_type(4))) float floatx4;

#define IN_F 512
#define OUT_F 512
#define BATCH 1024
#define C_PAD 36
#define K_SPLINE (IN_F * C_PAD)         // 18432
#define K_BASE_OFF K_SPLINE             // 18432
#define K_LIN_OFF (K_SPLINE + IN_F)     // 18944
#define K_PAD_OFF (K_SPLINE + 2 * IN_F) // 19456
#define K_TOT 20480                     // padded to /64 per split
#define SPLITS 32
#define KPS (K_TOT / SPLITS)            // 640
#define KIT (KPS / 64)                  // 10
#define MN (BATCH * OUT_F)              // 524288

static __device__ inline u16 f2b(float f) {
  union { float f; u32 u; } v; v.f = f;
  u32 r = v.u + 0x7FFFu + ((v.u >> 16) & 1u);  // round-nearest-even
  return (u16)(r >> 16);
}

// ---- mask dtype detector: int32 (flags=0) / uint8-bool (flags&1) / float32 (flags&2)
__global__ void detect_mask_kernel(const u32* __restrict__ m, int* __restrict__ flags) {
  int id = blockIdx.x * blockDim.x + threadIdx.x;  // 65536 words = 256KB scanned
  u32 w = m[id];
  if (w == 0x3F800000u) atomicOr(flags, 2);
  else if (w & 0xFFFFFF00u) atomicOr(flags, 1);
}

// ---- pack B: [o][k] bf16 rows, LDS-staged coalesced in and out
__global__ __launch_bounds__(256) void pack_b_kernel(
    const float* __restrict__ bw, const float* __restrict__ sw,
    const float* __restrict__ sc, const void* __restrict__ maskp,
    const int* __restrict__ flags, u16* __restrict__ B, float* __restrict__ bias) {
  __shared__ u64 lds64[1120 * 4];  // 35840B: float stage, reused as u16 rows
  float* lds_f = (float*)lds64;
  u16* lds_u = (u16*)lds64;

  int t = threadIdx.x, blk = blockIdx.x;
  int id = blk * 256 + t;            // o*512+i
  int o = id >> 9, i = id & 511;
  int i0 = (blk & 1) * 256;

  const float* swb = sw + ((size_t)o * 512 + i0) * 35;
#pragma unroll
  for (int j = 0; j < 35; ++j) lds_f[j * 256 + t] = swb[j * 256 + t];

  int fl = *flags;
  bool mk;
  if (fl & 2)      mk = ((const float*)maskp)[id] != 0.0f;
  else if (fl & 1) mk = ((const unsigned char*)maskp)[id] != 0;
  else             mk = ((const int*)maskp)[id] != 0;

  float s = sc[id];
  __syncthreads();
  float w[35];
#pragma unroll
  for (int c = 0; c < 35; ++c) w[c] = lds_f[t * 35 + c] * s;
  __syncthreads();

  // linear fallback params from endpoint spline values (dx = 2 exactly)
  float ys = (w[0] + 4.0f * w[1] + w[2]) * (1.0f / 6.0f);
  float ye = (w[32] + 4.0f * w[33] + w[34]) * (1.0f / 6.0f);
  float a = (ye - ys) * 0.5f;
  float bl = ys + a;

#pragma unroll
  for (int c = 0; c < 35; ++c) lds_u[t * 36 + c] = f2b(mk ? 0.0f : w[c]);
  lds_u[t * 36 + 35] = 0;

  B[(size_t)o * K_TOT + K_BASE_OFF + i] = f2b(bw[id]);
  B[(size_t)o * K_TOT + K_LIN_OFF + i] = f2b(mk ? a : 0.0f);
  // zero the K pad region (1024 u16 = 128 u64 per row, split over this row's 2 blocks)
  if (t < 64)
    ((u64*)(B + (size_t)o * K_TOT + K_PAD_OFF))[(blk & 1) * 64 + t] = 0ull;
  if (mk) atomicAdd(&bias[o], bl);
  __syncthreads();

  u64* dst = (u64*)(B + (size_t)o * K_TOT + (size_t)i0 * C_PAD);
#pragma unroll
  for (int j = 0; j < 9; ++j) dst[j * 256 + t] = lds64[j * 256 + t];
}

// ---- pack A: [b][k] bf16 rows, LDS-staged coalesced out
__global__ __launch_bounds__(256) void pack_a_kernel(const float* __restrict__ x,
                                                     u16* __restrict__ A) {
  __shared__ u64 lds64[2304];  // 256*36 u16 = 18432B
  u16* lds_u = (u16*)lds64;
  int t = threadIdx.x, blk = blockIdx.x;
  int id = blk * 256 + t;            // b*512+i
  int b = id >> 9, i = id & 511;
  int i0 = (blk & 1) * 256;
  float xv = x[id];

  int m = (int)floorf((xv + 1.1875f) * 16.0f);
  float gm = (float)m * 0.0625f - 1.1875f;
  if (xv < gm) { m -= 1; gm -= 0.0625f; }
  else if (xv >= gm + 0.0625f) { m += 1; gm += 0.0625f; }

  bool ok = (m >= 0) && (m <= 37);
  float B0 = 0.f, B1 = 0.f, B2 = 0.f, B3 = 0.f;
  if (ok) {
    float t_ = (xv - gm) * 16.0f;
    float t2 = t_ * t_, t3 = t2 * t_;
    float omt = 1.0f - t_;
    B0 = omt * omt * omt * (1.0f / 6.0f);
    B1 = (3.0f * t3 - 6.0f * t2 + 4.0f) * (1.0f / 6.0f);
    B2 = (-3.0f * t3 + 3.0f * t2 + 3.0f * t_ + 1.0f) * (1.0f / 6.0f);
    B3 = t3 * (1.0f / 6.0f);
  }

#pragma unroll
  for (int c = 0; c < C_PAD; ++c) {
    float v = 0.0f;
    if (ok && c <= 34) {
      if (c == m - 3) v = B0;
      else if (c == m - 2) v = B1;
      else if (c == m - 1) v = B2;
      else if (c == m) v = B3;
    }
    lds_u[t * 36 + c] = f2b(v);
  }

  float sl = xv / (1.0f + __expf(-xv));
  A[(size_t)b * K_TOT + K_BASE_OFF + i] = f2b(sl);
  A[(size_t)b * K_TOT + K_LIN_OFF + i] = f2b(xv);
  if (t < 64)
    ((u64*)(A + (size_t)b * K_TOT + K_PAD_OFF))[(blk & 1) * 64 + t] = 0ull;
  __syncthreads();

  u64* dst = (u64*)(A + (size_t)b * K_TOT + (size_t)i0 * C_PAD);
#pragma unroll
  for (int j = 0; j < 9; ++j) dst[j * 256 + t] = lds64[j * 256 + t];
}

// ---- init d_out with per-o bias (atomic-fallback path only)
__global__ void init_out_kernel(const float* __restrict__ bias, float* __restrict__ out) {
  int id = blockIdx.x * blockDim.x + threadIdx.x;
  out[id] = bias[id & 511];
}

// ---- split-K GEMM, 128x128 tile, BK=64, mfma_f32_16x16x32_bf16
// grid 1024 1D; ks = id&31 so all 32 blocks of one ks share an XCD.
// LDS layout XOR-swizzled: chunk c (8 u16) of row r lives at slot c^(r&7).
__global__ __launch_bounds__(256) void gemm_kernel(const u16* __restrict__ A,
                                                   const u16* __restrict__ Bp,
                                                   float* __restrict__ dst,
                                                   int partialMode) {
  __shared__ u16 As[128 * 64];
  __shared__ u16 Bs[128 * 64];
  int t = threadIdx.x;
  int id = blockIdx.x;
  int ks = id & 31, rem = id >> 5;
  int bm = rem & 7, bn = rem >> 3;
  int w = t >> 6, l = t & 63;
  int wm = w & 1, wn = w >> 1;

  floatx4 acc[4][4];
#pragma unroll
  for (int p = 0; p < 4; ++p)
#pragma unroll
    for (int q = 0; q < 4; ++q) acc[p][q] = (floatx4)0.0f;

  int ra = t >> 3;                      // staging row 0..31 (4 passes of 32 rows)
  int cg = (t & 7) ^ (ra & 7);          // swizzled source chunk for this lane's slot
  const u16* Ag = A + (size_t)(bm * 128 + ra) * K_TOT + (size_t)ks * KPS + cg * 8;
  const u16* Bg = Bp + (size_t)(bn * 128 + ra) * K_TOT + (size_t)ks * KPS + cg * 8;
  u16* Asp = &As[t * 8];                // slot = ra*64 + (t&7)*8 (lane-contiguous 16B)
  u16* Bsp = &Bs[t * 8];

  int mr = l & 15;
  int cq = l >> 4;                      // k-chunk within a 32-half: 0..3

  for (int kk = 0; kk < KIT; ++kk) {
#pragma unroll
    for (int p = 0; p < 4; ++p) {
      __builtin_amdgcn_global_load_lds(
          (const __attribute__((address_space(1))) void*)(Ag + (size_t)p * 32 * K_TOT),
          (__attribute__((address_space(3))) void*)(Asp + p * 2048), 16, 0, 0);
      __builtin_amdgcn_global_load_lds(
          (const __attribute__((address_space(1))) void*)(Bg + (size_t)p * 32 * K_TOT),
          (__attribute__((address_space(3))) void*)(Bsp + p * 2048), 16, 0, 0);
    }
    Ag += 64; Bg += 64;
    __syncthreads();

#pragma unroll
    for (int h = 0; h < 2; ++h) {
      short8 af[4], bf[4];
      int c = h * 4 + cq;
#pragma unroll
      for (int tm = 0; tm < 4; ++tm) {
        int row = wm * 64 + tm * 16 + mr;
        af[tm] = *(const short8*)&As[row * 64 + ((c ^ (row & 7)) << 3)];
      }
#pragma unroll
      for (int tn = 0; tn < 4; ++tn) {
        int row = wn * 64 + tn * 16 + mr;
        bf[tn] = *(const short8*)&Bs[row * 64 + ((c ^ (row & 7)) << 3)];
      }
#pragma unroll
      for (int tm = 0; tm < 4; ++tm)
#pragma unroll
        for (int tn = 0; tn < 4; ++tn)
          acc[tm][tn] = __builtin_amdgcn_mfma_f32_16x16x32_bf16(af[tm], bf[tn], acc[tm][tn], 0, 0, 0);
    }
    __syncthreads();
  }

  // C/D layout: col=lane&15 (n), row=(lane>>4)*4+reg (m)
  int r0 = bm * 128 + wm * 64 + ((l >> 4) << 2);
  int c0 = bn * 128 + wn * 64 + (l & 15);
  if (partialMode) {
    float* P = dst + (size_t)ks * MN;
#pragma unroll
    for (int tm = 0; tm < 4; ++tm)
#pragma unroll
      for (int tn = 0; tn < 4; ++tn)
#pragma unroll
        for (int r = 0; r < 4; ++r)
          P[(size_t)(r0 + tm * 16 + r) * OUT_F + c0 + tn * 16] = acc[tm][tn][r];
  } else {
#pragma unroll
    for (int tm = 0; tm < 4; ++tm)
#pragma unroll
      for (int tn = 0; tn < 4; ++tn)
#pragma unroll
        for (int r = 0; r < 4; ++r)
          atomicAdd(&dst[(size_t)(r0 + tm * 16 + r) * OUT_F + c0 + tn * 16], acc[tm][tn][r]);
  }
}

// ---- reduce 32 partials + bias -> out (float4)
__global__ __launch_bounds__(256) void reduce_kernel(const float* __restrict__ P,
                                                     const float* __restrict__ bias,
                                                     float* __restrict__ out) {
  int id = blockIdx.x * blockDim.x + threadIdx.x;  // 131072 float4s
  floatx4 s = ((const floatx4*)bias)[id & 127];
#pragma unroll
  for (int ks = 0; ks < SPLITS; ++ks) {
    floatx4 p = ((const floatx4*)P)[(size_t)ks * (MN / 4) + id];
    s.x += p.x; s.y += p.y; s.z += p.z; s.w += p.w;
  }
  ((floatx4*)out)[id] = s;
}

extern "C" void kernel_launch(void* const* d_in, const int* in_sizes, int n_in,
                              void* d_out, int out_size, void* d_ws, size_t ws_size,
                              hipStream_t stream) {
  const float* x  = (const float*)d_in[0];
  const float* bw = (const float*)d_in[1];
  const float* sw = (const float*)d_in[2];
  const float* sc = (const float*)d_in[3];
  // d_in[4] = grid: uniform h=1/16 extended knots, constants baked in.
  const void* mask = d_in[5];

  const size_t A_BYTES = (size_t)BATCH * K_TOT * 2;   // 41,943,040
  const size_t B_BYTES = (size_t)OUT_F * K_TOT * 2;   // 20,971,520
  const size_t P_OFF = A_BYTES + B_BYTES + 4096;
  const size_t P_BYTES = (size_t)SPLITS * MN * 4;     // 67,108,864

  char* wsb = (char*)d_ws;
  u16* Apack = (u16*)wsb;
  u16* Bpack = (u16*)(wsb + A_BYTES);
  float* bias = (float*)(wsb + A_BYTES + B_BYTES);
  int* flags = (int*)(wsb + A_BYTES + B_BYTES + 2048);
  float* P = (float*)(wsb + P_OFF);
  int partialMode = (ws_size >= P_OFF + P_BYTES) ? 1 : 0;

  hipMemsetAsync(wsb + A_BYTES + B_BYTES, 0, 4096, stream);
  detect_mask_kernel<<<256, 256, 0, stream>>>((const u32*)mask, flags);
  pack_b_kernel<<<1024, 256, 0, stream>>>(bw, sw, sc, mask, flags, Bpack, bias);
  pack_a_kernel<<<2048, 256, 0, stream>>>(x, Apack);
  if (partialMode) {
    gemm_kernel<<<SPLITS * 32, 256, 0, stream>>>(Apack, Bpack, P, 1);
    reduce_kernel<<<MN / 4 / 256, 256, 0, stream>>>(P, bias, (float*)d_out);
  } else {
    init_out_kernel<<<MN / 256, 256, 0, stream>>>(bias, (float*)d_out);
    gemm_kernel<<<SPLITS * 32, 256, 0, stream>>>(Apack, Bpack, (float*)d_out, 0);
  }
}

// Round 4
// 175.487 us; speedup vs baseline: 1.0226x; 1.0226x over previous
//
#include <hip/hip_runtime.h>
#include <hip/hip_bf16.h>

// SegmentDeactivation: KAN layer folded into one bf16 GEMM.
// K = 512*36 (dense-ified 4-sparse cubic B-spline bases) + 512 (silu(x)·W_base)
//   + 512 (x·masked-slope) = 19456 = 19*1024. bias = sum of masked intercepts.
// R4: A-pack fused into GEMM (bases built in LDS per tile, x staged in LDS),
//     SPLITS=19 (no K pad), bf16 tile-contiguous partials via LDS repack epilogue.

typedef unsigned short u16;
typedef unsigned int u32;
typedef unsigned long long u64;
typedef __attribute__((ext_vector_type(8))) short short8;
typedef __attribute__((ext_vector_type(4))) float floatx4;
typedef __attribute__((ext_vector_type(4))) unsigned int uintx4;

#define IN_F 512
#define OUT_F 512
#define BATCH 1024
#define C_PAD 36
#define K_SPLINE (IN_F * C_PAD)         // 18432
#define K_BASE_OFF K_SPLINE             // 18432
#define K_LIN_OFF (K_SPLINE + IN_F)     // 18944
#define K_TOT (K_SPLINE + 2 * IN_F)     // 19456 = 19*1024
#define SPLITS 19
#define KPS 1024
#define KIT 16                          // KPS/64
#define MN (BATCH * OUT_F)

static __device__ inline u16 f2b(float f) {
  union { float f; u32 u; } v; v.f = f;
  u32 r = v.u + 0x7FFFu + ((v.u >> 16) & 1u);  // round-nearest-even
  return (u16)(r >> 16);
}

// ---- mask dtype detector: int32 (flags=0) / uint8-bool (flags&1) / float32 (flags&2)
__global__ void detect_mask_kernel(const u32* __restrict__ m, int* __restrict__ flags) {
  int id = blockIdx.x * blockDim.x + threadIdx.x;  // 65536 words = 256KB scanned
  u32 w = m[id];
  if (w == 0x3F800000u) atomicOr(flags, 2);
  else if (w & 0xFFFFFF00u) atomicOr(flags, 1);
}

// ---- pack B: [o][k] bf16 rows, LDS-staged coalesced in and out
__global__ __launch_bounds__(256) void pack_b_kernel(
    const float* __restrict__ bw, const float* __restrict__ sw,
    const float* __restrict__ sc, const void* __restrict__ maskp,
    const int* __restrict__ flags, u16* __restrict__ B, float* __restrict__ bias) {
  __shared__ u64 lds64[1120 * 4];  // 35840B: float stage, reused as u16 rows
  float* lds_f = (float*)lds64;
  u16* lds_u = (u16*)lds64;

  int t = threadIdx.x, blk = blockIdx.x;
  int id = blk * 256 + t;            // o*512+i
  int o = id >> 9, i = id & 511;
  int i0 = (blk & 1) * 256;

  const float* swb = sw + ((size_t)o * 512 + i0) * 35;
#pragma unroll
  for (int j = 0; j < 35; ++j) lds_f[j * 256 + t] = swb[j * 256 + t];

  int fl = *flags;
  bool mk;
  if (fl & 2)      mk = ((const float*)maskp)[id] != 0.0f;
  else if (fl & 1) mk = ((const unsigned char*)maskp)[id] != 0;
  else             mk = ((const int*)maskp)[id] != 0;

  float s = sc[id];
  __syncthreads();
  float w[35];
#pragma unroll
  for (int c = 0; c < 35; ++c) w[c] = lds_f[t * 35 + c] * s;
  __syncthreads();

  // linear fallback params from endpoint spline values (dx = 2 exactly)
  float ys = (w[0] + 4.0f * w[1] + w[2]) * (1.0f / 6.0f);
  float ye = (w[32] + 4.0f * w[33] + w[34]) * (1.0f / 6.0f);
  float a = (ye - ys) * 0.5f;
  float bl = ys + a;

#pragma unroll
  for (int c = 0; c < 35; ++c) lds_u[t * 36 + c] = f2b(mk ? 0.0f : w[c]);
  lds_u[t * 36 + 35] = 0;

  B[(size_t)o * K_TOT + K_BASE_OFF + i] = f2b(bw[id]);
  B[(size_t)o * K_TOT + K_LIN_OFF + i] = f2b(mk ? a : 0.0f);
  if (mk) atomicAdd(&bias[o], bl);
  __syncthreads();

  u64* dst = (u64*)(B + (size_t)o * K_TOT + (size_t)i0 * C_PAD);
#pragma unroll
  for (int j = 0; j < 9; ++j) dst[j * 256 + t] = lds64[j * 256 + t];
}

// ---- fused GEMM: builds A-tile (spline bases / silu / x) in LDS, B staged via
// global_load_lds, 128x128 tile, BK=64, 16x16x32 bf16 MFMA, bf16 partial tiles out.
// grid 608 = 32 tiles x 19 splits; id = tid*19 + ks.
__global__ __launch_bounds__(256) void gemm_fused(const float* __restrict__ x,
                                                  const u16* __restrict__ Bp,
                                                  u16* __restrict__ P) {
  __shared__ __align__(16) char smem[49664];  // As 16K | Bs 16K | Xs 16.9K ; epilogue reuses as 128x136 u16
  u16* As = (u16*)smem;
  u16* Bs = (u16*)(smem + 16384);
  float* Xs = (float*)(smem + 32768);

  int t = threadIdx.x;
  int id = blockIdx.x;
  int ks = id % 19;
  int tid = id / 19;                 // 0..31
  int bm = tid >> 2, bn = tid & 3;
  int w = t >> 6, l = t & 63;
  int wm = w & 1, wn = w >> 1;

  floatx4 acc[4][4];
#pragma unroll
  for (int p = 0; p < 4; ++p)
#pragma unroll
    for (int q = 0; q < 4; ++q) acc[p][q] = (floatx4)0.0f;

  int k0s = ks * KPS;
  bool spline = (ks < 18);
  int i_blk_lo = k0s / 36;

  // B staging params (XOR-swizzled chunks, wave-uniform-base + lane*16 dest)
  int ra = t >> 3;
  int cg = (t & 7) ^ (ra & 7);
  const u16* Bg = Bp + (size_t)(bn * 128 + ra) * K_TOT + k0s + cg * 8;
  u16* Bsp = Bs + t * 8;

  if (spline) {
    // stage x slice: 128 rows x 32 i-slots (stride 33 floats, conflict-free)
#pragma unroll
    for (int p = 0; p < 16; ++p) {
      int idx = t + 256 * p;         // 0..4095
      int row = idx >> 5, ii = idx & 31;
      int i = i_blk_lo + ii;
      float v = (i < IN_F) ? x[(size_t)(bm * 128 + row) * IN_F + i] : 0.0f;
      Xs[row * 33 + ii] = v;
    }
    __syncthreads();
  }

  int mr = l & 15;
  int cq = l >> 4;

  for (int kk = 0; kk < KIT; ++kk) {
    int k0 = k0s + kk * 64;
    // issue B loads early
#pragma unroll
    for (int p = 0; p < 4; ++p)
      __builtin_amdgcn_global_load_lds(
          (const __attribute__((address_space(1))) void*)(Bg + (size_t)p * 32 * K_TOT),
          (__attribute__((address_space(3))) void*)(Bsp + p * 2048), 16, 0, 0);
    Bg += 64;

    if (spline) {
      // zero As (16KB, b128 per thread x4)
#pragma unroll
      for (int p = 0; p < 4; ++p) ((uintx4*)As)[t * 4 + p] = (uintx4)0u;
      __syncthreads();
      // scatter bases: pairs (row, ii), ii over the <=3 i-groups in this 64-window
      int i_lo = k0 / 36;
      int ni = (k0 + 63) / 36 - i_lo + 1;
#pragma unroll
      for (int pp = 0; pp < 2; ++pp) {
        int p = t + 256 * pp;
        int row = p & 127, ii = p >> 7;
        if (ii < ni) {
          int i = i_lo + ii;
          float xv = Xs[row * 33 + (i - i_blk_lo)];
          int mc = (int)floorf((xv + 1.1875f) * 16.0f);
          float gm = (float)mc * 0.0625f - 1.1875f;
          if (xv < gm) { mc -= 1; gm -= 0.0625f; }
          else if (xv >= gm + 0.0625f) { mc += 1; gm += 0.0625f; }
          if (mc >= 0 && mc <= 37) {
            float t_ = (xv - gm) * 16.0f;
            float t2 = t_ * t_, t3 = t2 * t_;
            float omt = 1.0f - t_;
            float Bv[4];
            Bv[0] = omt * omt * omt * (1.0f / 6.0f);
            Bv[1] = (3.0f * t3 - 6.0f * t2 + 4.0f) * (1.0f / 6.0f);
            Bv[2] = (-3.0f * t3 + 3.0f * t2 + 3.0f * t_ + 1.0f) * (1.0f / 6.0f);
            Bv[3] = t3 * (1.0f / 6.0f);
            int cbase = i * 36 - k0;
#pragma unroll
            for (int j = 0; j < 4; ++j) {
              int c = mc - 3 + j;
              int col = cbase + c;
              if (c >= 0 && c <= 34 && col >= 0 && col < 64) {
                int ch = col >> 3;
                As[row * 64 + ((ch ^ (row & 7)) << 3) + (col & 7)] = f2b(Bv[j]);
              }
            }
          }
        }
      }
    } else {
      // ks==18: cols = base region (kk<8: silu(x)) then linear region (x)
      int ib0 = (kk & 7) * 64;
      bool isBase = (kk < 8);
#pragma unroll
      for (int p = 0; p < 4; ++p) {
        int cid = t + 256 * p;       // 0..1023 = (row, chunk)
        int row = cid >> 3, ch = cid & 7;
        const float* xp = &x[(size_t)(bm * 128 + row) * IN_F + ib0 + ch * 8];
        floatx4 v0 = *(const floatx4*)xp;
        floatx4 v1 = *(const floatx4*)(xp + 4);
        float f[8] = {v0.x, v0.y, v0.z, v0.w, v1.x, v1.y, v1.z, v1.w};
        u16 r[8];
#pragma unroll
        for (int j = 0; j < 8; ++j) {
          float vv = f[j];
          if (isBase) vv = vv / (1.0f + __expf(-vv));
          r[j] = f2b(vv);
        }
        *(short8*)(As + row * 64 + ((ch ^ (row & 7)) << 3)) = *(short8*)r;
      }
    }
    __syncthreads();

    // MFMA phase
#pragma unroll
    for (int h = 0; h < 2; ++h) {
      short8 af[4], bf[4];
      int c = h * 4 + cq;
#pragma unroll
      for (int tm = 0; tm < 4; ++tm) {
        int row = wm * 64 + tm * 16 + mr;
        af[tm] = *(const short8*)&As[row * 64 + ((c ^ (row & 7)) << 3)];
      }
#pragma unroll
      for (int tn = 0; tn < 4; ++tn) {
        int row = wn * 64 + tn * 16 + mr;
        bf[tn] = *(const short8*)&Bs[row * 64 + ((c ^ (row & 7)) << 3)];
      }
#pragma unroll
      for (int tm = 0; tm < 4; ++tm)
#pragma unroll
        for (int tn = 0; tn < 4; ++tn)
          acc[tm][tn] = __builtin_amdgcn_mfma_f32_16x16x32_bf16(af[tm], bf[tn], acc[tm][tn], 0, 0, 0);
    }
    __syncthreads();
  }

  // ---- epilogue: acc -> LDS (128x136 u16) -> coalesced bf16 tile store
  u16* ldc = (u16*)smem;
  int r0 = wm * 64 + ((l >> 4) << 2);
  int c0 = wn * 64 + (l & 15);
#pragma unroll
  for (int tm = 0; tm < 4; ++tm)
#pragma unroll
    for (int tn = 0; tn < 4; ++tn)
#pragma unroll
      for (int r = 0; r < 4; ++r)
        ldc[(r0 + tm * 16 + r) * 136 + c0 + tn * 16] = f2b(acc[tm][tn][r]);
  __syncthreads();

  u16* Pb = P + (size_t)(tid * 19 + ks) * 16384;
  int row = t >> 1, half = t & 1;
#pragma unroll
  for (int q = 0; q < 8; ++q) {
    short8 v = *(const short8*)(ldc + row * 136 + half * 64 + q * 8);
    *(short8*)(Pb + row * 128 + half * 64 + q * 8) = v;
  }
}

// ---- reduce 19 bf16 partial tiles + bias -> fp32 out
__global__ __launch_bounds__(256) void reduce_kernel(const u16* __restrict__ P,
                                                     const float* __restrict__ bias,
                                                     float* __restrict__ out) {
  int cid = blockIdx.x * 256 + threadIdx.x;  // 65536 chunks of 8 cols
  int row = cid >> 6;
  int c8 = (cid & 63) << 3;
  int tid = ((row >> 7) << 2) + (c8 >> 7);
  size_t off = (size_t)(row & 127) * 128 + (c8 & 127);
  const u16* base = P + (size_t)tid * 19 * 16384 + off;

  float s[8];
  floatx4 b0 = *(const floatx4*)(bias + c8);
  floatx4 b1 = *(const floatx4*)(bias + c8 + 4);
  s[0] = b0.x; s[1] = b0.y; s[2] = b0.z; s[3] = b0.w;
  s[4] = b1.x; s[5] = b1.y; s[6] = b1.z; s[7] = b1.w;
#pragma unroll
  for (int ks = 0; ks < SPLITS; ++ks) {
    short8 v = *(const short8*)(base + (size_t)ks * 16384);
#pragma unroll
    for (int j = 0; j < 8; ++j) {
      union { u32 u; float f; } cv; cv.u = ((u32)(u16)v[j]) << 16;
      s[j] += cv.f;
    }
  }
  floatx4 o0 = {s[0], s[1], s[2], s[3]};
  floatx4 o1 = {s[4], s[5], s[6], s[7]};
  *(floatx4*)(out + (size_t)row * OUT_F + c8) = o0;
  *(floatx4*)(out + (size_t)row * OUT_F + c8 + 4) = o1;
}

extern "C" void kernel_launch(void* const* d_in, const int* in_sizes, int n_in,
                              void* d_out, int out_size, void* d_ws, size_t ws_size,
                              hipStream_t stream) {
  const float* x  = (const float*)d_in[0];
  const float* bw = (const float*)d_in[1];
  const float* sw = (const float*)d_in[2];
  const float* sc = (const float*)d_in[3];
  // d_in[4] = grid: uniform h=1/16 extended knots, constants baked in.
  const void* mask = d_in[5];

  const size_t B_BYTES = (size_t)OUT_F * K_TOT * 2;   // 19,922,944
  const size_t P_OFF = B_BYTES + 4096;
  char* wsb = (char*)d_ws;
  u16* Bpack = (u16*)wsb;
  float* bias = (float*)(wsb + B_BYTES);
  int* flags = (int*)(wsb + B_BYTES + 2048);
  u16* P = (u16*)(wsb + P_OFF);                       // 32*19*16384 u16 = 19.9 MB

  hipMemsetAsync(wsb + B_BYTES, 0, 4096, stream);
  detect_mask_kernel<<<256, 256, 0, stream>>>((const u32*)mask, flags);
  pack_b_kernel<<<1024, 256, 0, stream>>>(bw, sw, sc, mask, flags, Bpack, bias);
  gemm_fused<<<32 * SPLITS, 256, 0, stream>>>(x, Bpack, P);
  reduce_kernel<<<MN / 8 / 256, 256, 0, stream>>>(P, bias, (float*)d_out);
}

// Round 5
// 169.600 us; speedup vs baseline: 1.0581x; 1.0347x over previous
//
#include <hip/hip_runtime.h>
#include <hip/hip_bf16.h>

// SegmentDeactivation: KAN layer folded into one bf16 GEMM.
// K = 512*36 (dense-ified 4-sparse cubic B-spline bases) + 512 (silu(x)·W_base)
//   + 512 (x·masked-slope) = 19456 = 38*512. bias = sum of masked intercepts.
// R5: per-(b,i) basis precompute ([i][b] layout, 16B struct), conflict-free
//     zero-fill, SPLITS=38 (grid 1216), direct coalesced bf16 partial stores,
//     reduce decodes MFMA C-layout and folds bias.

typedef unsigned short u16;
typedef unsigned int u32;
typedef unsigned long long u64;
typedef __attribute__((ext_vector_type(8))) short short8;
typedef __attribute__((ext_vector_type(4))) float floatx4;
typedef __attribute__((ext_vector_type(4))) unsigned int uintx4;

#define IN_F 512
#define OUT_F 512
#define BATCH 1024
#define K_SPLINE (IN_F * 36)            // 18432
#define K_BASE_OFF K_SPLINE
#define K_LIN_OFF (K_SPLINE + IN_F)
#define K_TOT (K_SPLINE + 2 * IN_F)     // 19456 = 38*512
#define SPLITS 38
#define KPS 512
#define KIT 8                           // KPS/64
#define MN (BATCH * OUT_F)

static __device__ inline u16 f2b(float f) {
  union { float f; u32 u; } v; v.f = f;
  u32 r = v.u + 0x7FFFu + ((v.u >> 16) & 1u);  // round-nearest-even
  return (u16)(r >> 16);
}

// ---- mask dtype detector: int32 (flags=0) / uint8-bool (flags&1) / float32 (flags&2)
__global__ void detect_mask_kernel(const u32* __restrict__ m, int* __restrict__ flags) {
  int id = blockIdx.x * blockDim.x + threadIdx.x;  // 65536 words = 256KB scanned
  u32 w = m[id];
  if (w == 0x3F800000u) atomicOr(flags, 2);
  else if (w & 0xFFFFFF00u) atomicOr(flags, 1);
}

// ---- pack B: [o][k] bf16 rows, LDS-staged coalesced in and out
__global__ __launch_bounds__(256) void pack_b_kernel(
    const float* __restrict__ bw, const float* __restrict__ sw,
    const float* __restrict__ sc, const void* __restrict__ maskp,
    const int* __restrict__ flags, u16* __restrict__ B, float* __restrict__ bias) {
  __shared__ u64 lds64[1120 * 4];  // 35840B: float stage, reused as u16 rows
  float* lds_f = (float*)lds64;
  u16* lds_u = (u16*)lds64;

  int t = threadIdx.x, blk = blockIdx.x;
  int id = blk * 256 + t;            // o*512+i
  int o = id >> 9, i = id & 511;
  int i0 = (blk & 1) * 256;

  const float* swb = sw + ((size_t)o * 512 + i0) * 35;
#pragma unroll
  for (int j = 0; j < 35; ++j) lds_f[j * 256 + t] = swb[j * 256 + t];

  int fl = *flags;
  bool mk;
  if (fl & 2)      mk = ((const float*)maskp)[id] != 0.0f;
  else if (fl & 1) mk = ((const unsigned char*)maskp)[id] != 0;
  else             mk = ((const int*)maskp)[id] != 0;

  float s = sc[id];
  __syncthreads();
  float w[35];
#pragma unroll
  for (int c = 0; c < 35; ++c) w[c] = lds_f[t * 35 + c] * s;
  __syncthreads();

  // linear fallback params from endpoint spline values (dx = 2 exactly)
  float ys = (w[0] + 4.0f * w[1] + w[2]) * (1.0f / 6.0f);
  float ye = (w[32] + 4.0f * w[33] + w[34]) * (1.0f / 6.0f);
  float a = (ye - ys) * 0.5f;
  float bl = ys + a;

#pragma unroll
  for (int c = 0; c < 35; ++c) lds_u[t * 36 + c] = f2b(mk ? 0.0f : w[c]);
  lds_u[t * 36 + 35] = 0;

  B[(size_t)o * K_TOT + K_BASE_OFF + i] = f2b(bw[id]);
  B[(size_t)o * K_TOT + K_LIN_OFF + i] = f2b(mk ? a : 0.0f);
  if (mk) atomicAdd(&bias[o], bl);
  __syncthreads();

  u64* dst = (u64*)(B + (size_t)o * K_TOT + (size_t)i0 * 36);
#pragma unroll
  for (int j = 0; j < 9; ++j) dst[j * 256 + t] = lds64[j * 256 + t];
}

// ---- precompute per-(b,i) basis: PB[i*1024 + b] = {b0|b1<<16, b2|b3<<16, cell, 0}
__global__ __launch_bounds__(256) void pack_basis_kernel(const float* __restrict__ x,
                                                         uintx4* __restrict__ PB) {
  int id = blockIdx.x * 256 + threadIdx.x;   // i*1024 + b
  int i = id >> 10, b = id & 1023;
  float xv = x[(size_t)b * IN_F + i];

  int mc = (int)floorf((xv + 1.1875f) * 16.0f);
  float gm = (float)mc * 0.0625f - 1.1875f;
  if (xv < gm) { mc -= 1; gm -= 0.0625f; }
  else if (xv >= gm + 0.0625f) { mc += 1; gm += 0.0625f; }

  u16 r0 = 0, r1 = 0, r2 = 0, r3 = 0;
  if (mc >= 0 && mc <= 37) {
    float t_ = (xv - gm) * 16.0f;
    float t2 = t_ * t_, t3 = t2 * t_;
    float omt = 1.0f - t_;
    r0 = f2b(omt * omt * omt * (1.0f / 6.0f));
    r1 = f2b((3.0f * t3 - 6.0f * t2 + 4.0f) * (1.0f / 6.0f));
    r2 = f2b((-3.0f * t3 + 3.0f * t2 + 3.0f * t_ + 1.0f) * (1.0f / 6.0f));
    r3 = f2b(t3 * (1.0f / 6.0f));
  } else {
    mc = 1 << 20;  // sentinel: no column ever matches
  }
  uintx4 e;
  e.x = (u32)r0 | ((u32)r1 << 16);
  e.y = (u32)r2 | ((u32)r3 << 16);
  e.z = (u32)mc;
  e.w = 0;
  PB[id] = e;
}

// ---- fused GEMM: A-tile built in LDS from PB (spline) or x (silu/linear),
// B staged via global_load_lds, 128x128 tile, BK=64, 16x16x32 bf16 MFMA.
// grid 1216: ks = id>>5 (0..37), tile = id&31, bm = tile>>2, bn = tile&3.
__global__ __launch_bounds__(256, 4) void gemm_fused(const float* __restrict__ x,
                                                     const uintx4* __restrict__ PB,
                                                     const u16* __restrict__ Bp,
                                                     u16* __restrict__ P) {
  __shared__ u16 As[128 * 64];   // 16KB
  __shared__ u16 Bs[128 * 64];   // 16KB

  int t = threadIdx.x;
  int id = blockIdx.x;
  int ks = id >> 5, tile = id & 31;
  int bm = tile >> 2, bn = tile & 3;
  int w = t >> 6, l = t & 63;
  int wm = w & 1, wn = w >> 1;

  floatx4 acc[4][4];
#pragma unroll
  for (int p = 0; p < 4; ++p)
#pragma unroll
    for (int q = 0; q < 4; ++q) acc[p][q] = (floatx4)0.0f;

  int k0s = ks * KPS;
  bool spline = (ks < 36);

  // B staging params (XOR-swizzled chunks, wave-uniform-base + lane*16 dest)
  int ra = t >> 3;
  int cg = (t & 7) ^ (ra & 7);
  const u16* Bg = Bp + (size_t)(bn * 128 + ra) * K_TOT + k0s + cg * 8;
  u16* Bsp = Bs + t * 8;

  int mr = l & 15;
  int cq = l >> 4;

  for (int kk = 0; kk < KIT; ++kk) {
    int k0 = k0s + kk * 64;

    if (spline) {
      // zero As: lane-contiguous b128, conflict-free
#pragma unroll
      for (int p = 0; p < 4; ++p) ((uintx4*)As)[(p << 8) + t] = (uintx4)0u;
      __syncthreads();
      // issue B loads (drain overlaps scatter)
#pragma unroll
      for (int p = 0; p < 4; ++p)
        __builtin_amdgcn_global_load_lds(
            (const __attribute__((address_space(1))) void*)(Bg + (size_t)p * 32 * K_TOT),
            (__attribute__((address_space(3))) void*)(Bsp + p * 2048), 16, 0, 0);
      Bg += 64;
      // scatter 4 basis values per (row, ii)
      int i_lo = k0 / 36;
      int ni = (k0 + 63) / 36 - i_lo + 1;
#pragma unroll
      for (int pp = 0; pp < 2; ++pp) {
        int p = t + 256 * pp;
        int row = p & 127, ii = p >> 7;
        if (ii < ni) {
          int i = i_lo + ii;
          uintx4 e = PB[(size_t)(i << 10) + bm * 128 + row];
          int mc = (int)e.z;
          int colb = i * 36 - k0 + mc - 3;  // col of j=0
          u16 bv[4] = {(u16)e.x, (u16)(e.x >> 16), (u16)e.y, (u16)(e.y >> 16)};
#pragma unroll
          for (int j = 0; j < 4; ++j) {
            int c = mc - 3 + j;
            int col = colb + j;
            if ((u32)c <= 34u && (u32)col < 64u)
              As[row * 64 + (((col >> 3) ^ (row & 7)) << 3) + (col & 7)] = bv[j];
          }
        }
      }
    } else {
      // ks==36: silu(x) cols; ks==37: x cols. Full 64-col fill, no zero pass.
#pragma unroll
      for (int p = 0; p < 4; ++p)
        __builtin_amdgcn_global_load_lds(
            (const __attribute__((address_space(1))) void*)(Bg + (size_t)p * 32 * K_TOT),
            (__attribute__((address_space(3))) void*)(Bsp + p * 2048), 16, 0, 0);
      Bg += 64;
      bool isBase = (ks == 36);
#pragma unroll
      for (int p = 0; p < 4; ++p) {
        int cid = t + 256 * p;       // (row, chunk)
        int row = cid >> 3, ch = cid & 7;
        int xi = kk * 64 + ch * 8;
        const float* xp = &x[(size_t)(bm * 128 + row) * IN_F + xi];
        floatx4 v0 = *(const floatx4*)xp;
        floatx4 v1 = *(const floatx4*)(xp + 4);
        float f[8] = {v0.x, v0.y, v0.z, v0.w, v1.x, v1.y, v1.z, v1.w};
        u16 r[8];
#pragma unroll
        for (int j = 0; j < 8; ++j) {
          float vv = f[j];
          if (isBase) vv = vv / (1.0f + __expf(-vv));
          r[j] = f2b(vv);
        }
        *(short8*)(As + row * 64 + ((ch ^ (row & 7)) << 3)) = *(short8*)r;
      }
    }
    __syncthreads();

    // MFMA phase
#pragma unroll
    for (int h = 0; h < 2; ++h) {
      short8 af[4], bf[4];
      int c = h * 4 + cq;
#pragma unroll
      for (int tm = 0; tm < 4; ++tm) {
        int row = wm * 64 + tm * 16 + mr;
        af[tm] = *(const short8*)&As[row * 64 + ((c ^ (row & 7)) << 3)];
      }
#pragma unroll
      for (int tn = 0; tn < 4; ++tn) {
        int row = wn * 64 + tn * 16 + mr;
        bf[tn] = *(const short8*)&Bs[row * 64 + ((c ^ (row & 7)) << 3)];
      }
#pragma unroll
      for (int tm = 0; tm < 4; ++tm)
#pragma unroll
        for (int tn = 0; tn < 4; ++tn)
          acc[tm][tn] = __builtin_amdgcn_mfma_f32_16x16x32_bf16(af[tm], bf[tn], acc[tm][tn], 0, 0, 0);
    }
    __syncthreads();
  }

  // ---- epilogue: direct coalesced bf16 partial store, fixed per-thread layout.
  // value v = tm*16 + tn*4 + r stored at chunk q=v>>3, elem j=v&7, addr q*2048+t*8+j.
  u16* Pb = P + ((size_t)tile * SPLITS + ks) * 16384;
#pragma unroll
  for (int q = 0; q < 8; ++q) {
    int tm = q >> 1, tn0 = (q & 1) * 2;
    u16 r[8];
#pragma unroll
    for (int z = 0; z < 4; ++z) r[z] = f2b(acc[tm][tn0][z]);
#pragma unroll
    for (int z = 0; z < 4; ++z) r[4 + z] = f2b(acc[tm][tn0 + 1][z]);
    *(short8*)(Pb + q * 2048 + t * 8) = *(short8*)r;
  }
}

// ---- reduce 38 bf16 partial tiles + bias -> fp32 out (decodes C-layout)
__global__ __launch_bounds__(256) void reduce_kernel(const u16* __restrict__ P,
                                                     const float* __restrict__ bias,
                                                     float* __restrict__ out) {
  int rid = blockIdx.x * 256 + threadIdx.x;  // 65536 = tile*2048 + q*256 + t
  int tile = rid >> 11;
  int rem = rid & 2047;
  int q = rem >> 8, t = rem & 255;
  const u16* base = P + (size_t)tile * SPLITS * 16384 + q * 2048 + t * 8;

  float s[8] = {0, 0, 0, 0, 0, 0, 0, 0};
#pragma unroll
  for (int ks = 0; ks < SPLITS; ++ks) {
    short8 v = *(const short8*)(base + (size_t)ks * 16384);
#pragma unroll
    for (int j = 0; j < 8; ++j) {
      union { u32 u; float f; } cv; cv.u = ((u32)(u16)v[j]) << 16;
      s[j] += cv.f;
    }
  }

  int w = t >> 6, l = t & 63;
  int wm = w & 1, wn = w >> 1;
  int bm = tile >> 2, bn = tile & 3;
  int row0 = bm * 128 + wm * 64 + ((l >> 4) << 2);
  int col0 = bn * 128 + wn * 64 + (l & 15);
  int tm = q >> 1, tn0 = (q & 1) * 2;
#pragma unroll
  for (int j = 0; j < 8; ++j) {
    int tn = tn0 + (j >> 2), rr = j & 3;
    int row = row0 + tm * 16 + rr;
    int col = col0 + tn * 16;
    out[(size_t)row * OUT_F + col] = s[j] + bias[col];
  }
}

extern "C" void kernel_launch(void* const* d_in, const int* in_sizes, int n_in,
                              void* d_out, int out_size, void* d_ws, size_t ws_size,
                              hipStream_t stream) {
  const float* x  = (const float*)d_in[0];
  const float* bw = (const float*)d_in[1];
  const float* sw = (const float*)d_in[2];
  const float* sc = (const float*)d_in[3];
  // d_in[4] = grid: uniform h=1/16 extended knots, constants baked in.
  const void* mask = d_in[5];

  const size_t B_BYTES = (size_t)OUT_F * K_TOT * 2;         // 19,922,944
  const size_t PB_OFF = B_BYTES + 4096;
  const size_t PB_BYTES = (size_t)MN * 16;                  // 8,388,608
  const size_t P_OFF = PB_OFF + PB_BYTES;                   // P: 39,845,888

  char* wsb = (char*)d_ws;
  u16* Bpack = (u16*)wsb;
  float* bias = (float*)(wsb + B_BYTES);
  int* flags = (int*)(wsb + B_BYTES + 2048);
  uintx4* PB = (uintx4*)(wsb + PB_OFF);
  u16* P = (u16*)(wsb + P_OFF);

  hipMemsetAsync(wsb + B_BYTES, 0, 4096, stream);
  detect_mask_kernel<<<256, 256, 0, stream>>>((const u32*)mask, flags);
  pack_b_kernel<<<1024, 256, 0, stream>>>(bw, sw, sc, mask, flags, Bpack, bias);
  pack_basis_kernel<<<2048, 256, 0, stream>>>(x, PB);
  gemm_fused<<<32 * SPLITS, 256, 0, stream>>>(x, PB, Bpack, P);
  reduce_kernel<<<256, 256, 0, stream>>>(P, bias, (float*)d_out);
}